// Round 1
// 2316.147 us; speedup vs baseline: 1.9313x; 1.9313x over previous
//
#include <hip/hip_runtime.h>

// Seq2Seq LSTM (2-layer enc + 2-layer dec, teacher forcing) + vocab projection.
// Round 3: persistent-kernel rewrite.
//   - 95% of round-2 time was 130 serial lstm_step launches (weights re-read
//     and fp32->bf16 re-converted every step, 64 WGs, launch overhead).
//   - Now: one-time weight convert (bf16 ws) + bias convert (f32 ws);
//     layer-0 x-projections (emb@Wih^T, no recurrence) precomputed for all t
//     as a parallel GEMM into gx[t][2048][32] f32;
//     ONE persistent kernel, 64 co-resident WGs (chain A = e0->d0,
//     chain B = e1->d1, pipelined diagonally), weights + cell state c in
//     REGISTERS, h exchanged via global bf16 buffers with an agent-scope
//     atomic barrier per step (129 barriers).
//   - out_gemm: grid flattened, M-tiles fastest + XCD-chunked swizzle so the
//     16 blocks sharing a lin_W N-slice share one XCD L2; non-temporal output
//     stores so 262 MB of streaming writes stop evicting lin_W from L2.
// Workspace: ~59 MB (y bufs 8M, wbf16 16M, gx 2x16M, misc).

#define BATCH 32
#define T 64
#define HID 512
#define VOCAB 32000
#define BOS 1

typedef unsigned short u16;
typedef unsigned int u32;
typedef __attribute__((ext_vector_type(8))) short bf16x8;
typedef __attribute__((ext_vector_type(4))) float f32x4;

static constexpr size_t MATSZ = (size_t)2048 * 512;   // elems per weight matrix

__device__ __forceinline__ float bf2f(u16 u) {
  return __uint_as_float(((u32)u) << 16);
}
__device__ __forceinline__ short f2bfs(float f) {
  u32 x = __float_as_uint(f);
  u32 r = x + 0x7fffu + ((x >> 16) & 1u);   // RNE; no NaNs in this workload
  return (short)(r >> 16);
}

// Load 8 consecutive external-float elements as bf16x8.
template<bool BF16>
__device__ __forceinline__ bf16x8 ldext8(const void* base, size_t off) {
  if constexpr (BF16) {
    return *(const bf16x8*)((const u16*)base + off);
  } else {
    const float* p = (const float*)base + off;
    float4 a = *(const float4*)p;
    float4 b = *(const float4*)(p + 4);
    bf16x8 r;
    r[0] = f2bfs(a.x); r[1] = f2bfs(a.y); r[2] = f2bfs(a.z); r[3] = f2bfs(a.w);
    r[4] = f2bfs(b.x); r[5] = f2bfs(b.y); r[6] = f2bfs(b.z); r[7] = f2bfs(b.w);
    return r;
  }
}
template<bool BF16>
__device__ __forceinline__ float ldext1(const void* base, size_t off) {
  if constexpr (BF16) return bf2f(((const u16*)base)[off]);
  else return ((const float*)base)[off];
}

// ---------------- dtype probe (unchanged): classify external floats bf16 vs fp32.
__global__ void dtype_probe(const u32* __restrict__ w, int* __restrict__ flag) {
  __shared__ int cnt;
  if (threadIdx.x == 0) cnt = 0;
  __syncthreads();
  int c = 0;
  for (int i = threadIdx.x; i < 1024; i += 256) {
    u16 lo = (u16)(w[i] & 0xFFFFu);
    int e = (lo >> 7) & 0xFF;
    if (e >= 0x68 && e <= 0x7E) c++;
  }
  atomicAdd(&cnt, c);
  __syncthreads();
  if (threadIdx.x == 0) *flag = (cnt > 512) ? 1 : 0;   // 1 => bf16
}

// ---------------- init: zero h_zero + barrier counter (per launch!)
__global__ void init_ws(u16* hz, int* bar) {
  int i = blockIdx.x * 256 + threadIdx.x;   // 64*256 == BATCH*HID
  hz[i] = 0;
  if (i == 0) *bar = 0;
}

struct Ptr8 { const void* p[8]; };

// ---------------- one-time weight convert: 8 matrices [2048][512] -> bf16 ws
__global__ __launch_bounds__(256) void convert_w(Ptr8 s, u16* __restrict__ dst,
                                                 const int* __restrict__ flag) {
  const int m = blockIdx.z;                 // matrix 0..7
  const int i = (blockIdx.x * 256 + threadIdx.x) * 4;   // grid.x=1024 -> 1M elems
  u16* d = dst + (size_t)m * MATSZ + i;
  if (*flag) {
    *(ushort4*)d = *(const ushort4*)((const u16*)s.p[m] + i);
  } else {
    const float* sp = (const float*)s.p[m] + i;
    float4 v = *(const float4*)sp;
    ushort4 o;
    o.x = (u16)f2bfs(v.x); o.y = (u16)f2bfs(v.y);
    o.z = (u16)f2bfs(v.z); o.w = (u16)f2bfs(v.w);
    *(ushort4*)d = o;
  }
}

// ---------------- one-time bias convert: 4 biases [2048] -> f32 ws
__global__ __launch_bounds__(256) void convert_b(Ptr8 s, float* __restrict__ dst,
                                                 const int* __restrict__ flag) {
  const int l = blockIdx.z;                 // layer 0..3
  const int i = blockIdx.x * 256 + threadIdx.x;   // grid.x=8 -> 2048
  dst[l * 2048 + i] = (*flag) ? bf2f(((const u16*)s.p[l])[i])
                              : ((const float*)s.p[l])[i];
}

// ---------------- gx precompute: layer-0 x-projection for ALL steps (parallel).
// gx[t][grow(2048)][batch(32)] f32 = emb[tok[b][t(_-1)]] @ Wih^T  (no bias).
template<bool BF16>
__device__ __forceinline__ void gx_body(const int* __restrict__ tokens,
                                        const void* __restrict__ emb,
                                        const u16* __restrict__ wihb,
                                        float* __restrict__ gx, int shift) {
  const int tid = threadIdx.x, lane = tid & 63, w = tid >> 6;
  const int fr = lane & 15, q8 = (lane >> 4) * 8, q4 = (lane >> 4) * 4;
  const int j0 = blockIdx.x * 16;
  const int t = blockIdx.y;
  int t0, t1;
  if (shift) {
    t0 = (t == 0) ? BOS : tokens[fr * T + t - 1];
    t1 = (t == 0) ? BOS : tokens[(fr + 16) * T + t - 1];
  } else {
    t0 = tokens[fr * T + t];
    t1 = tokens[(fr + 16) * T + t];
  }
  const int grow = w * 512 + j0 + fr;
  const u16* wp = wihb + (size_t)grow * 512;
  const size_t e0 = (size_t)t0 * 512, e1 = (size_t)t1 * 512;
  f32x4 acc0 = {0.f, 0.f, 0.f, 0.f}, acc1 = {0.f, 0.f, 0.f, 0.f};
#pragma unroll 4
  for (int ks = 0; ks < 512; ks += 32) {
    bf16x8 b = *(const bf16x8*)(wp + ks + q8);
    bf16x8 a0 = ldext8<BF16>(emb, e0 + ks + q8);
    bf16x8 a1 = ldext8<BF16>(emb, e1 + ks + q8);
    acc0 = __builtin_amdgcn_mfma_f32_16x16x32_bf16(a0, b, acc0, 0, 0, 0);
    acc1 = __builtin_amdgcn_mfma_f32_16x16x32_bf16(a1, b, acc1, 0, 0, 0);
  }
  // D layout: col(=hidden)=lane&15 (== fr == grow's row), row(=batch)=q4+reg
  float* gp = gx + ((size_t)t * 2048 + grow) * 32;
  *(f32x4*)(gp + q4) = acc0;
  *(f32x4*)(gp + 16 + q4) = acc1;
}

__global__ __launch_bounds__(256) void gx_gemm_bf16(
    const int* xtok, const int* dtok, const void* eemb, const void* demb,
    const u16* wbf, float* gxe, float* gxd, const int* __restrict__ flag) {
  if (!*flag) return;
  if (blockIdx.z == 0) gx_body<true>(xtok, eemb, wbf, gxe, 0);
  else                 gx_body<true>(dtok, demb, wbf + 4 * MATSZ, gxd, 1);
}
__global__ __launch_bounds__(256) void gx_gemm_f32(
    const int* xtok, const int* dtok, const void* eemb, const void* demb,
    const u16* wbf, float* gxe, float* gxd, const int* __restrict__ flag) {
  if (*flag) return;
  if (blockIdx.z == 0) gx_body<false>(xtok, eemb, wbf, gxe, 0);
  else                 gx_body<false>(dtok, demb, wbf + 4 * MATSZ, gxd, 1);
}

// ---------------- persistent LSTM kernel.
// 64 WGs x 256 thr. wg<32: chain A (e0 steps 0..63 then d0). wg>=32: chain B
// (e1 then d1), lagging one global step. Weights (bf16) + c (f32) in registers.
// One agent-scope barrier per global step; y (=h) via global bf16 buffers.
struct PArgs {
  const u16* wbf;       // 8 bf16 matrices [2048][512]
  const float* biasf;   // [4][2048] f32
  const float* gxe;     // [64][2048][32] f32
  const float* gxd;
  const u16* hzero;     // [32][512] bf16 zeros
  u16* ye0; u16* ye1; u16* yd0; u16* yd1;   // [64][32][512] bf16 each
  int* bar;
};

__global__ __launch_bounds__(256) void lstm_persist(PArgs A) {
  const int wg = blockIdx.x;          // 0..63
  const bool chB = wg >= 32;
  const int j0 = (wg & 31) * 16;
  const int tid = threadIdx.x;
  const int lane = tid & 63;
  const int w = tid >> 6;             // wave == gate (i,f,g,o)
  const int fr = lane & 15;
  const int q8 = (lane >> 4) * 8;
  const int q4 = (lane >> 4) * 4;
  const int NB = BATCH * HID;
  __shared__ float gsh[4][16][33];

  const int bb0 = (tid * 2) & 31,     jj0 = (tid * 2) >> 5;
  const int bb1 = (tid * 2 + 1) & 31, jj1 = (tid * 2 + 1) >> 5;

  bf16x8 wih[16], whh[16];            // statically indexed -> registers
  float b0i = 0, b0f = 0, b0g = 0, b0o = 0;
  float b1i = 0, b1f = 0, b1g = 0, b1o = 0;
  float c0 = 0.f, c1 = 0.f;           // cell state lives in registers; e->d carries over
  const int row = w * 512 + j0 + fr;  // this lane's gate row

  for (int k = 0; k < 129; ++k) {
    const int t = chB ? (k - 1) : k;
    if (t >= 0 && t < 128) {
      const int tt = t & 63;
      const bool dec = t >= 64;
      if (tt == 0) {                  // phase start: (re)load weights + biases
        const int layer = (dec ? 2 : 0) + (chB ? 1 : 0);
        const u16* whp = A.wbf + (size_t)(2 * layer + 1) * MATSZ + (size_t)row * 512;
#pragma unroll
        for (int kf = 0; kf < 16; ++kf)
          whh[kf] = *(const bf16x8*)(whp + kf * 32 + q8);
        if (chB) {
          const u16* wip = A.wbf + (size_t)(2 * layer) * MATSZ + (size_t)row * 512;
#pragma unroll
          for (int kf = 0; kf < 16; ++kf)
            wih[kf] = *(const bf16x8*)(wip + kf * 32 + q8);
        }
        const float* bp = A.biasf + layer * 2048 + j0;
        b0i = bp[jj0]; b0f = bp[512 + jj0]; b0g = bp[1024 + jj0]; b0o = bp[1536 + jj0];
        b1i = bp[jj1]; b1f = bp[512 + jj1]; b1g = bp[1024 + jj1]; b1o = bp[1536 + jj1];
      }
      const u16 *h_in, *x_in = nullptr;
      u16* y_out;
      const float* gx = nullptr;
      if (!chB) {
        if (!dec) {
          h_in = (tt == 0) ? A.hzero : A.ye0 + (size_t)(tt - 1) * NB;
          y_out = A.ye0 + (size_t)tt * NB;
          gx = A.gxe + (size_t)tt * 2048 * 32;
        } else {
          h_in = (tt == 0) ? A.ye0 + (size_t)63 * NB : A.yd0 + (size_t)(tt - 1) * NB;
          y_out = A.yd0 + (size_t)tt * NB;
          gx = A.gxd + (size_t)tt * 2048 * 32;
        }
      } else {
        if (!dec) {
          x_in = A.ye0 + (size_t)tt * NB;
          h_in = (tt == 0) ? A.hzero : A.ye1 + (size_t)(tt - 1) * NB;
          y_out = A.ye1 + (size_t)tt * NB;
        } else {
          x_in = A.yd0 + (size_t)tt * NB;
          h_in = (tt == 0) ? A.ye1 + (size_t)63 * NB : A.yd1 + (size_t)(tt - 1) * NB;
          y_out = A.yd1 + (size_t)tt * NB;
        }
      }

      f32x4 acc0, acc1;
      if (!chB) {
        // layer-0: acc starts from precomputed x-projection, add h@Whh^T
        const float* gp = gx + (size_t)row * 32;
        acc0 = *(const f32x4*)(gp + q4);
        acc1 = *(const f32x4*)(gp + 16 + q4);
#pragma unroll
        for (int kf = 0; kf < 16; ++kf) {
          bf16x8 h0 = *(const bf16x8*)(h_in + fr * 512 + kf * 32 + q8);
          bf16x8 h1 = *(const bf16x8*)(h_in + (fr + 16) * 512 + kf * 32 + q8);
          acc0 = __builtin_amdgcn_mfma_f32_16x16x32_bf16(h0, whh[kf], acc0, 0, 0, 0);
          acc1 = __builtin_amdgcn_mfma_f32_16x16x32_bf16(h1, whh[kf], acc1, 0, 0, 0);
        }
      } else {
        // layer-1: x@Wih^T + h@Whh^T, 4 independent 16-deep MFMA chains
        f32x4 x0a = {0, 0, 0, 0}, x1a = {0, 0, 0, 0};
        f32x4 h0a = {0, 0, 0, 0}, h1a = {0, 0, 0, 0};
#pragma unroll
        for (int kf = 0; kf < 16; ++kf) {
          bf16x8 xa = *(const bf16x8*)(x_in + fr * 512 + kf * 32 + q8);
          bf16x8 xb = *(const bf16x8*)(x_in + (fr + 16) * 512 + kf * 32 + q8);
          bf16x8 ha = *(const bf16x8*)(h_in + fr * 512 + kf * 32 + q8);
          bf16x8 hb = *(const bf16x8*)(h_in + (fr + 16) * 512 + kf * 32 + q8);
          x0a = __builtin_amdgcn_mfma_f32_16x16x32_bf16(xa, wih[kf], x0a, 0, 0, 0);
          x1a = __builtin_amdgcn_mfma_f32_16x16x32_bf16(xb, wih[kf], x1a, 0, 0, 0);
          h0a = __builtin_amdgcn_mfma_f32_16x16x32_bf16(ha, whh[kf], h0a, 0, 0, 0);
          h1a = __builtin_amdgcn_mfma_f32_16x16x32_bf16(hb, whh[kf], h1a, 0, 0, 0);
        }
        acc0 = x0a + h0a;
        acc1 = x1a + h1a;
      }

      // D layout: col(=hidden jj)=lane&15, row(=batch)=(lane>>4)*4+reg
#pragma unroll
      for (int r = 0; r < 4; ++r) {
        gsh[w][fr][q4 + r] = acc0[r];          // batches 0..15
        gsh[w][fr][16 + q4 + r] = acc1[r];     // batches 16..31
      }
      __syncthreads();

      // cell update: 512 (b,j) states per WG, 2 per thread, c in registers
      {
        float gi = gsh[0][jj0][bb0] + b0i;
        float gf = gsh[1][jj0][bb0] + b0f;
        float gg = gsh[2][jj0][bb0] + b0g;
        float go = gsh[3][jj0][bb0] + b0o;
        float si = 1.f / (1.f + __expf(-gi));
        float sf = 1.f / (1.f + __expf(-gf));
        float so = 1.f / (1.f + __expf(-go));
        float cn = sf * c0 + si * tanhf(gg);
        c0 = cn;
        y_out[bb0 * 512 + j0 + jj0] = (u16)f2bfs(so * tanhf(cn));

        gi = gsh[0][jj1][bb1] + b1i;
        gf = gsh[1][jj1][bb1] + b1f;
        gg = gsh[2][jj1][bb1] + b1g;
        go = gsh[3][jj1][bb1] + b1o;
        si = 1.f / (1.f + __expf(-gi));
        sf = 1.f / (1.f + __expf(-gf));
        so = 1.f / (1.f + __expf(-go));
        cn = sf * c1 + si * tanhf(gg);
        c1 = cn;
        y_out[bb1 * 512 + j0 + jj1] = (u16)f2bfs(so * tanhf(cn));
      }
    }

    // ---- global step barrier (all 64 WGs, active or not) ----
    __syncthreads();                       // drains this WG's stores (vmcnt 0)
    if (tid == 0) {
      // release: writes back this XCD's L2 to the coherence point, then bump
      __hip_atomic_fetch_add(A.bar, 1, __ATOMIC_RELEASE, __HIP_MEMORY_SCOPE_AGENT);
      const int tgt = 64 * (k + 1);
      while (__hip_atomic_load(A.bar, __ATOMIC_RELAXED, __HIP_MEMORY_SCOPE_AGENT) < tgt)
        __builtin_amdgcn_s_sleep(1);
      __threadfence();                     // acquire: invalidate stale L1/L2
    }
    __syncthreads();
  }
}

// ---------------- projection GEMM: out[b][t][v] = u2[t][b][:] . lin_W[v][:] + lin_b[v]
// Grid flattened to 4000 blocks; XCD-chunked swizzle + M-fastest so the 16
// blocks sharing a lin_W N-slice are concurrent on one XCD L2. NT stores.
template<bool BF16>
__device__ __forceinline__ void out_gemm_body(const u16* __restrict__ A,
                                              const void* __restrict__ Wv,
                                              const void* __restrict__ bias,
                                              void* __restrict__ out) {
  __shared__ __align__(16) u16 As[128 * 40];
  __shared__ __align__(16) u16 Bs[128 * 40];
  const int hw = blockIdx.x;                       // 0..3999
  const int logical = (hw & 7) * 500 + (hw >> 3);  // XCD-chunked (4000%8==0)
  const int m0 = (logical & 15) * 128;             // M fastest: 16 tiles
  const int n0 = (logical >> 4) * 128;             // 250 N tiles
  const int tid = threadIdx.x;
  const int lane = tid & 63;
  const int wv = tid >> 6;
  const int wm = wv >> 1, wn = wv & 1;
  const int fr = lane & 15, q8 = (lane >> 4) * 8;
  const int r0 = tid >> 2;
  const int c8 = (tid & 3) * 8;

  f32x4 acc[4][4] = {};

  for (int k0 = 0; k0 < 512; k0 += 32) {
    __syncthreads();
    *(uint4*)&As[r0 * 40 + c8]        = *(const uint4*)&A[(size_t)(m0 + r0) * 512 + k0 + c8];
    *(uint4*)&As[(r0 + 64) * 40 + c8] = *(const uint4*)&A[(size_t)(m0 + r0 + 64) * 512 + k0 + c8];
    *(bf16x8*)&Bs[r0 * 40 + c8]        = ldext8<BF16>(Wv, (size_t)(n0 + r0) * 512 + k0 + c8);
    *(bf16x8*)&Bs[(r0 + 64) * 40 + c8] = ldext8<BF16>(Wv, (size_t)(n0 + r0 + 64) * 512 + k0 + c8);
    __syncthreads();
    bf16x8 af[4], bg[4];
#pragma unroll
    for (int i = 0; i < 4; ++i) {
      af[i] = *(const bf16x8*)&As[(wm * 64 + i * 16 + fr) * 40 + q8];
      bg[i] = *(const bf16x8*)&Bs[(wn * 64 + i * 16 + fr) * 40 + q8];
    }
#pragma unroll
    for (int i = 0; i < 4; ++i)
#pragma unroll
      for (int j = 0; j < 4; ++j)
        acc[i][j] = __builtin_amdgcn_mfma_f32_16x16x32_bf16(af[i], bg[j], acc[i][j], 0, 0, 0);
  }

  const int cl = lane & 15;
  const int rq = (lane >> 4) * 4;
#pragma unroll
  for (int j = 0; j < 4; ++j) {
    int n = n0 + wn * 64 + j * 16 + cl;
    float bv = ldext1<BF16>(bias, n);
#pragma unroll
    for (int i = 0; i < 4; ++i) {
#pragma unroll
      for (int r = 0; r < 4; ++r) {
        int m = m0 + wm * 64 + i * 16 + rq + r;
        int tt = m >> 5, bb = m & 31;
        size_t oidx = ((size_t)bb * T + tt) * VOCAB + n;
        float v = acc[i][j][r] + bv;
        if constexpr (BF16) __builtin_nontemporal_store((u16)f2bfs(v), (u16*)out + oidx);
        else                __builtin_nontemporal_store(v, (float*)out + oidx);
      }
    }
  }
}

__global__ __launch_bounds__(256) void out_gemm_bf16(const u16* A, const void* Wv,
                                                     const void* bias, void* out,
                                                     const int* __restrict__ flag) {
  if (!*flag) return;
  out_gemm_body<true>(A, Wv, bias, out);
}
__global__ __launch_bounds__(256) void out_gemm_f32(const u16* A, const void* Wv,
                                                    const void* bias, void* out,
                                                    const int* __restrict__ flag) {
  if (*flag) return;
  out_gemm_body<false>(A, Wv, bias, out);
}

extern "C" void kernel_launch(void* const* d_in, const int* in_sizes, int n_in,
                              void* d_out, int out_size, void* d_ws, size_t ws_size,
                              hipStream_t stream) {
  (void)in_sizes; (void)n_in; (void)out_size; (void)ws_size;
  const int* x = (const int*)d_in[0];
  const int* tgt = (const int*)d_in[1];
  const void* enc_emb = d_in[2];
  const void* dec_emb = d_in[3];
  const void* Wih[4] = {d_in[4], d_in[7], d_in[10], d_in[13]};
  const void* Whh[4] = {d_in[5], d_in[8], d_in[11], d_in[14]};
  const void* bias[4] = {d_in[6], d_in[9], d_in[12], d_in[15]};
  const void* lin_W = d_in[16];
  const void* lin_b = d_in[17];

  char* ws = (char*)d_ws;
  u16* y_e0   = (u16*)(ws + 0x000000);     // [T][B][H] bf16, 2MB each
  u16* y_e1   = (u16*)(ws + 0x200000);
  u16* y_d0   = (u16*)(ws + 0x400000);
  u16* y_d1   = (u16*)(ws + 0x600000);     // == u2 == GEMM A
  u16* h_zero = (u16*)(ws + 0x800000);     // [B][H] bf16 zeros
  int* flag   = (int*)(ws + 0x810000);
  int* bar    = (int*)(ws + 0x810100);     // persistent-kernel barrier counter
  float* biasf = (float*)(ws + 0x820000);  // [4][2048] f32
  u16* wbf    = (u16*)(ws + 0x830000);     // 8 x [2048][512] bf16 = 16 MB
  float* gxe  = (float*)(ws + 0x1830000);  // [64][2048][32] f32 = 16 MB
  float* gxd  = (float*)(ws + 0x2830000);  // 16 MB; end 0x3830000 (~59 MB)

  dtype_probe<<<dim3(1), 256, 0, stream>>>((const u32*)lin_W, flag);
  init_ws<<<dim3(64), 256, 0, stream>>>(h_zero, bar);

  Ptr8 wsrc;
  for (int l = 0; l < 4; ++l) { wsrc.p[2 * l] = Wih[l]; wsrc.p[2 * l + 1] = Whh[l]; }
  convert_w<<<dim3(1024, 1, 8), 256, 0, stream>>>(wsrc, wbf, flag);

  Ptr8 bsrc = {};
  for (int l = 0; l < 4; ++l) bsrc.p[l] = bias[l];
  convert_b<<<dim3(8, 1, 4), 256, 0, stream>>>(bsrc, biasf, flag);

  gx_gemm_bf16<<<dim3(32, 64, 2), 256, 0, stream>>>(x, tgt, enc_emb, dec_emb, wbf, gxe, gxd, flag);
  gx_gemm_f32 <<<dim3(32, 64, 2), 256, 0, stream>>>(x, tgt, enc_emb, dec_emb, wbf, gxe, gxd, flag);

  PArgs pa;
  pa.wbf = wbf; pa.biasf = biasf; pa.gxe = gxe; pa.gxd = gxd;
  pa.hzero = h_zero;
  pa.ye0 = y_e0; pa.ye1 = y_e1; pa.yd0 = y_d0; pa.yd1 = y_d1;
  pa.bar = bar;
  lstm_persist<<<dim3(64), 256, 0, stream>>>(pa);

  out_gemm_bf16<<<dim3(4000), 256, 0, stream>>>(y_d1, lin_W, lin_b, d_out, flag);
  out_gemm_f32 <<<dim3(4000), 256, 0, stream>>>(y_d1, lin_W, lin_b, d_out, flag);
}

// Round 2
// 1892.790 us; speedup vs baseline: 2.3633x; 1.2237x over previous
//
#include <hip/hip_runtime.h>

// Seq2Seq LSTM (2-layer enc + 2-layer dec, teacher forcing) + vocab projection.
// Round 4: fused-chain persistent kernel + fence-free barrier.
//   - Round-3 persist ran at 12.4 us/step (MfmaUtil 0.6%): cost was the
//     RELEASE wbl2 + acquire-invalidate fences and 64-participant barrier,
//     not data volume.
//   - Now: 32 WGs, each owning a 16-hidden slice of BOTH layer-0 (chain A:
//     e0->d0, Whh only, x-projection precomputed in gx) and layer-1 (chain B:
//     e1->d1, Wih+Whh). A's h-input == B's x-input (ye0/yd0[k-1]) -> staged
//     ONCE per step into padded LDS (row stride 520 u16 = odd 16B units ->
//     conflict-free ds_read_b128). Weights in registers (192 VGPRs,
//     __launch_bounds__(256,1)).
//   - y stores are agent-scope RELAXED ATOMIC stores (write-through, no dirty
//     L2) -> barrier needs no release-wbl2 and no acquire-invalidate: stores
//     drained by __syncthreads (vmcnt 0), then relaxed fetch_add + relaxed
//     poll. Safe because every y t-slice is written once per launch and only
//     read at later steps (no stale-line hazard).
//   - gx/weight/bias loads issue BEFORE the barrier poll (barrier-independent).
// Workspace layout unchanged (~59 MB).

#define BATCH 32
#define T 64
#define HID 512
#define VOCAB 32000
#define BOS 1
#define NB (BATCH * HID)

typedef unsigned short u16;
typedef unsigned int u32;
typedef __attribute__((ext_vector_type(8))) short bf16x8;
typedef __attribute__((ext_vector_type(4))) float f32x4;

static constexpr size_t MATSZ = (size_t)2048 * 512;   // elems per weight matrix

__device__ __forceinline__ float bf2f(u16 u) {
  return __uint_as_float(((u32)u) << 16);
}
__device__ __forceinline__ short f2bfs(float f) {
  u32 x = __float_as_uint(f);
  u32 r = x + 0x7fffu + ((x >> 16) & 1u);   // RNE; no NaNs in this workload
  return (short)(r >> 16);
}

// Load 8 consecutive external-float elements as bf16x8.
template<bool BF16>
__device__ __forceinline__ bf16x8 ldext8(const void* base, size_t off) {
  if constexpr (BF16) {
    return *(const bf16x8*)((const u16*)base + off);
  } else {
    const float* p = (const float*)base + off;
    float4 a = *(const float4*)p;
    float4 b = *(const float4*)(p + 4);
    bf16x8 r;
    r[0] = f2bfs(a.x); r[1] = f2bfs(a.y); r[2] = f2bfs(a.z); r[3] = f2bfs(a.w);
    r[4] = f2bfs(b.x); r[5] = f2bfs(b.y); r[6] = f2bfs(b.z); r[7] = f2bfs(b.w);
    return r;
  }
}
template<bool BF16>
__device__ __forceinline__ float ldext1(const void* base, size_t off) {
  if constexpr (BF16) return bf2f(((const u16*)base)[off]);
  else return ((const float*)base)[off];
}

// ---------------- dtype probe: classify external floats bf16 vs fp32.
__global__ void dtype_probe(const u32* __restrict__ w, int* __restrict__ flag) {
  __shared__ int cnt;
  if (threadIdx.x == 0) cnt = 0;
  __syncthreads();
  int c = 0;
  for (int i = threadIdx.x; i < 1024; i += 256) {
    u16 lo = (u16)(w[i] & 0xFFFFu);
    int e = (lo >> 7) & 0xFF;
    if (e >= 0x68 && e <= 0x7E) c++;
  }
  atomicAdd(&cnt, c);
  __syncthreads();
  if (threadIdx.x == 0) *flag = (cnt > 512) ? 1 : 0;   // 1 => bf16
}

// ---------------- init: zero h_zero + barrier counter (per launch!)
__global__ void init_ws(u16* hz, int* bar) {
  int i = blockIdx.x * 256 + threadIdx.x;   // 64*256 == BATCH*HID
  hz[i] = 0;
  if (i == 0) *bar = 0;
}

struct Ptr8 { const void* p[8]; };

// ---------------- one-time weight convert: 8 matrices [2048][512] -> bf16 ws
__global__ __launch_bounds__(256) void convert_w(Ptr8 s, u16* __restrict__ dst,
                                                 const int* __restrict__ flag) {
  const int m = blockIdx.z;                 // matrix 0..7
  const int i = (blockIdx.x * 256 + threadIdx.x) * 4;   // grid.x=1024 -> 1M elems
  u16* d = dst + (size_t)m * MATSZ + i;
  if (*flag) {
    *(ushort4*)d = *(const ushort4*)((const u16*)s.p[m] + i);
  } else {
    const float* sp = (const float*)s.p[m] + i;
    float4 v = *(const float4*)sp;
    ushort4 o;
    o.x = (u16)f2bfs(v.x); o.y = (u16)f2bfs(v.y);
    o.z = (u16)f2bfs(v.z); o.w = (u16)f2bfs(v.w);
    *(ushort4*)d = o;
  }
}

// ---------------- one-time bias convert: 4 biases [2048] -> f32 ws
__global__ __launch_bounds__(256) void convert_b(Ptr8 s, float* __restrict__ dst,
                                                 const int* __restrict__ flag) {
  const int l = blockIdx.z;                 // layer 0..3
  const int i = blockIdx.x * 256 + threadIdx.x;   // grid.x=8 -> 2048
  dst[l * 2048 + i] = (*flag) ? bf2f(((const u16*)s.p[l])[i])
                              : ((const float*)s.p[l])[i];
}

// ---------------- gx precompute: layer-0 x-projection for ALL steps (parallel).
// gx[t][grow(2048)][batch(32)] f32 = emb[tok[b][t(_-1)]] @ Wih^T  (no bias).
template<bool BF16>
__device__ __forceinline__ void gx_body(const int* __restrict__ tokens,
                                        const void* __restrict__ emb,
                                        const u16* __restrict__ wihb,
                                        float* __restrict__ gx, int shift) {
  const int tid = threadIdx.x, lane = tid & 63, w = tid >> 6;
  const int fr = lane & 15, q8 = (lane >> 4) * 8, q4 = (lane >> 4) * 4;
  const int j0 = blockIdx.x * 16;
  const int t = blockIdx.y;
  int t0, t1;
  if (shift) {
    t0 = (t == 0) ? BOS : tokens[fr * T + t - 1];
    t1 = (t == 0) ? BOS : tokens[(fr + 16) * T + t - 1];
  } else {
    t0 = tokens[fr * T + t];
    t1 = tokens[(fr + 16) * T + t];
  }
  const int grow = w * 512 + j0 + fr;
  const u16* wp = wihb + (size_t)grow * 512;
  const size_t e0 = (size_t)t0 * 512, e1 = (size_t)t1 * 512;
  f32x4 acc0 = {0.f, 0.f, 0.f, 0.f}, acc1 = {0.f, 0.f, 0.f, 0.f};
#pragma unroll 4
  for (int ks = 0; ks < 512; ks += 32) {
    bf16x8 b = *(const bf16x8*)(wp + ks + q8);
    bf16x8 a0 = ldext8<BF16>(emb, e0 + ks + q8);
    bf16x8 a1 = ldext8<BF16>(emb, e1 + ks + q8);
    acc0 = __builtin_amdgcn_mfma_f32_16x16x32_bf16(a0, b, acc0, 0, 0, 0);
    acc1 = __builtin_amdgcn_mfma_f32_16x16x32_bf16(a1, b, acc1, 0, 0, 0);
  }
  // D layout: col(=hidden)=lane&15 (== fr == grow's row), row(=batch)=q4+reg
  float* gp = gx + ((size_t)t * 2048 + grow) * 32;
  *(f32x4*)(gp + q4) = acc0;
  *(f32x4*)(gp + 16 + q4) = acc1;
}

__global__ __launch_bounds__(256) void gx_gemm_bf16(
    const int* xtok, const int* dtok, const void* eemb, const void* demb,
    const u16* wbf, float* gxe, float* gxd, const int* __restrict__ flag) {
  if (!*flag) return;
  if (blockIdx.z == 0) gx_body<true>(xtok, eemb, wbf, gxe, 0);
  else                 gx_body<true>(dtok, demb, wbf + 4 * MATSZ, gxd, 1);
}
__global__ __launch_bounds__(256) void gx_gemm_f32(
    const int* xtok, const int* dtok, const void* eemb, const void* demb,
    const u16* wbf, float* gxe, float* gxd, const int* __restrict__ flag) {
  if (*flag) return;
  if (blockIdx.z == 0) gx_body<false>(xtok, eemb, wbf, gxe, 0);
  else                 gx_body<false>(dtok, demb, wbf + 4 * MATSZ, gxd, 1);
}

// ---------------- persistent LSTM kernel (fused chains, fence-free barrier).
// 32 WGs x 256 thr, 1 WG/CU. WG wg owns hidden slice [wg*16, wg*16+16) of
// layer-0 (A: e0->d0) AND layer-1 (B: e1->d1). Global step k:
//   A computes layer-0 t=k   (k=0..127;  enc k<64, dec k>=64)
//   B computes layer-1 t=k-1 (k=1..128)
// A.h_in == B.x_in == ye0/yd0[step k-1] -> staged once in LDS (SX); B.h_in
// staged in SH. Weights+biases+c in registers. 128 global barriers.
struct PArgs {
  const u16* wbf;       // 8 bf16 matrices [2048][512]
  const float* biasf;   // [4][2048] f32
  const float* gxe;     // [64][2048][32] f32
  const float* gxd;
  const u16* hzero;     // [32][512] bf16 zeros
  u16* ye0; u16* ye1; u16* yd0; u16* yd1;   // [64][32][512] bf16 each
  int* bar;
};

__global__ __launch_bounds__(256, 1) void lstm_persist(PArgs A) {
  const int wg = blockIdx.x;          // 0..31
  const int j0 = wg * 16;
  const int tid = threadIdx.x;
  const int lane = tid & 63;
  const int w = tid >> 6;             // wave == gate (i,f,g,o)
  const int fr = lane & 15;
  const int q8 = (lane >> 4) * 8;
  const int q4 = (lane >> 4) * 4;
  const int row = w * HID + j0 + fr;  // this lane's gate row (weight B-operand)

  // padded LDS: row stride 520 u16 = 1040 B = 65 x 16B (odd) -> even bank-quad
  // distribution for both the staging ds_write_b128 and the MFMA ds_read_b128.
  __shared__ __align__(16) u16 SX[32 * 520];
  __shared__ __align__(16) u16 SH[32 * 520];
  __shared__ float gshA[4][16][33];
  __shared__ float gshB[4][16][33];

  bf16x8 whhA[16], wihB[16], whhB[16];   // 192 VGPRs of weights
  float bA[8], bB[8];                    // i0,i1,f0,f1,g0,g1,o0,o1 (jj0,jj1)
  float cA0 = 0.f, cA1 = 0.f, cB0 = 0.f, cB1 = 0.f;   // cell states (carry e->d)

  const int jj0 = (2 * tid) & 15;        // cell-update mapping: thread ->
  const int bb = tid >> 3;               // (batch bb, hidden jj0, jj0+1)

  auto loadW = [&](bf16x8* dst, int mat) {
    const u16* p = A.wbf + (size_t)mat * MATSZ + (size_t)row * HID + q8;
#pragma unroll
    for (int kf = 0; kf < 16; ++kf) dst[kf] = *(const bf16x8*)(p + kf * 32);
  };
  auto loadB = [&](float* d, int layer) {
    const float* bp = A.biasf + layer * 2048 + j0;
    d[0] = bp[jj0];        d[1] = bp[jj0 + 1];
    d[2] = bp[512 + jj0];  d[3] = bp[512 + jj0 + 1];
    d[4] = bp[1024 + jj0]; d[5] = bp[1024 + jj0 + 1];
    d[6] = bp[1536 + jj0]; d[7] = bp[1536 + jj0 + 1];
  };

  for (int k = 0; k <= 128; ++k) {
    const bool aAct = k < 128;
    const bool bAct = k >= 1;

    // arrival for step k-1 (our stores were drained by the trailing
    // __syncthreads of the previous iteration; stores are write-through).
    if (bAct && tid == 0)
      __hip_atomic_fetch_add(A.bar, 1, __ATOMIC_RELAXED, __HIP_MEMORY_SCOPE_AGENT);

    // ---- barrier-independent prefetch (overlaps the poll) ----
    f32x4 gxp0 = {0.f, 0.f, 0.f, 0.f}, gxp1 = {0.f, 0.f, 0.f, 0.f};
    if (aAct) {
      const float* gp = ((k < 64) ? A.gxe + (size_t)k * 65536
                                  : A.gxd + (size_t)(k - 64) * 65536)
                        + (size_t)row * 32;
      gxp0 = *(const f32x4*)(gp + q4);
      gxp1 = *(const f32x4*)(gp + 16 + q4);
    }
    if (k == 0)  { loadW(whhA, 1); loadW(wihB, 2); loadW(whhB, 3);
                   loadB(bA, 0); loadB(bB, 1); }
    if (k == 64) { loadW(whhA, 5); loadB(bA, 2); }
    if (k == 65) { loadW(wihB, 6); loadW(whhB, 7); loadB(bB, 3); }

    if (bAct && tid == 0) {
      const int tgt = 32 * k;
      while (__hip_atomic_load(A.bar, __ATOMIC_RELAXED, __HIP_MEMORY_SCOPE_AGENT) < tgt)
        __builtin_amdgcn_s_sleep(1);
    }
    __syncthreads();

    // ---- stage inputs to LDS (SX serves A.h and B.x; SH serves B.h) ----
    const u16* srcX = (k == 0)  ? A.hzero
                    : (k <= 64) ? A.ye0 + (size_t)(k - 1) * NB
                                : A.yd0 + (size_t)(k - 65) * NB;
    const u16* srcH = (k <= 1)  ? A.hzero
                    : (k <= 65) ? A.ye1 + (size_t)(k - 2) * NB
                                : A.yd1 + (size_t)(k - 66) * NB;
    {
      uint4 tx[8], th[8];
#pragma unroll
      for (int i = 0; i < 8; ++i) {
        const int q = i * 256 + tid, r = q >> 6, c = q & 63;
        tx[i] = *(const uint4*)(srcX + r * 512 + c * 8);
      }
      if (bAct) {
#pragma unroll
        for (int i = 0; i < 8; ++i) {
          const int q = i * 256 + tid, r = q >> 6, c = q & 63;
          th[i] = *(const uint4*)(srcH + r * 512 + c * 8);
        }
      }
#pragma unroll
      for (int i = 0; i < 8; ++i) {
        const int q = i * 256 + tid, r = q >> 6, c = q & 63;
        *(uint4*)&SX[r * 520 + c * 8] = tx[i];
      }
      if (bAct) {
#pragma unroll
        for (int i = 0; i < 8; ++i) {
          const int q = i * 256 + tid, r = q >> 6, c = q & 63;
          *(uint4*)&SH[r * 520 + c * 8] = th[i];
        }
      }
    }
    __syncthreads();

    // ---- MFMA: A: gx + h@WhhA ; B: x@WihB + h@WhhB (x == SX) ----
    const int rx0 = fr * 520 + q8, rx1 = (fr + 16) * 520 + q8;
    f32x4 accA0 = gxp0, accA1 = gxp1;
    f32x4 xb0 = {0,0,0,0}, xb1 = {0,0,0,0}, hb0 = {0,0,0,0}, hb1 = {0,0,0,0};
    if (aAct && bAct) {
#pragma unroll
      for (int kf = 0; kf < 16; ++kf) {
        bf16x8 a0 = *(const bf16x8*)&SX[rx0 + kf * 32];
        bf16x8 a1 = *(const bf16x8*)&SX[rx1 + kf * 32];
        bf16x8 h0 = *(const bf16x8*)&SH[rx0 + kf * 32];
        bf16x8 h1 = *(const bf16x8*)&SH[rx1 + kf * 32];
        accA0 = __builtin_amdgcn_mfma_f32_16x16x32_bf16(a0, whhA[kf], accA0, 0, 0, 0);
        accA1 = __builtin_amdgcn_mfma_f32_16x16x32_bf16(a1, whhA[kf], accA1, 0, 0, 0);
        xb0 = __builtin_amdgcn_mfma_f32_16x16x32_bf16(a0, wihB[kf], xb0, 0, 0, 0);
        xb1 = __builtin_amdgcn_mfma_f32_16x16x32_bf16(a1, wihB[kf], xb1, 0, 0, 0);
        hb0 = __builtin_amdgcn_mfma_f32_16x16x32_bf16(h0, whhB[kf], hb0, 0, 0, 0);
        hb1 = __builtin_amdgcn_mfma_f32_16x16x32_bf16(h1, whhB[kf], hb1, 0, 0, 0);
      }
    } else if (aAct) {                   // k == 0
#pragma unroll
      for (int kf = 0; kf < 16; ++kf) {
        bf16x8 a0 = *(const bf16x8*)&SX[rx0 + kf * 32];
        bf16x8 a1 = *(const bf16x8*)&SX[rx1 + kf * 32];
        accA0 = __builtin_amdgcn_mfma_f32_16x16x32_bf16(a0, whhA[kf], accA0, 0, 0, 0);
        accA1 = __builtin_amdgcn_mfma_f32_16x16x32_bf16(a1, whhA[kf], accA1, 0, 0, 0);
      }
    } else {                             // k == 128
#pragma unroll
      for (int kf = 0; kf < 16; ++kf) {
        bf16x8 a0 = *(const bf16x8*)&SX[rx0 + kf * 32];
        bf16x8 a1 = *(const bf16x8*)&SX[rx1 + kf * 32];
        bf16x8 h0 = *(const bf16x8*)&SH[rx0 + kf * 32];
        bf16x8 h1 = *(const bf16x8*)&SH[rx1 + kf * 32];
        xb0 = __builtin_amdgcn_mfma_f32_16x16x32_bf16(a0, wihB[kf], xb0, 0, 0, 0);
        xb1 = __builtin_amdgcn_mfma_f32_16x16x32_bf16(a1, wihB[kf], xb1, 0, 0, 0);
        hb0 = __builtin_amdgcn_mfma_f32_16x16x32_bf16(h0, whhB[kf], hb0, 0, 0, 0);
        hb1 = __builtin_amdgcn_mfma_f32_16x16x32_bf16(h1, whhB[kf], hb1, 0, 0, 0);
      }
    }

    // D layout: col(=hidden jj)=lane&15, row(=batch)=(lane>>4)*4+reg
    if (aAct) {
#pragma unroll
      for (int r = 0; r < 4; ++r) {
        gshA[w][fr][q4 + r] = accA0[r];
        gshA[w][fr][16 + q4 + r] = accA1[r];
      }
    }
    if (bAct) {
      f32x4 sb0 = xb0 + hb0, sb1 = xb1 + hb1;
#pragma unroll
      for (int r = 0; r < 4; ++r) {
        gshB[w][fr][q4 + r] = sb0[r];
        gshB[w][fr][16 + q4 + r] = sb1[r];
      }
    }
    __syncthreads();

    // ---- cell updates; y written via agent-scope write-through stores ----
    if (aAct) {
      u16* yA = (k < 64) ? A.ye0 + (size_t)k * NB : A.yd0 + (size_t)(k - 64) * NB;
      float gi0 = gshA[0][jj0][bb] + bA[0], gi1 = gshA[0][jj0 + 1][bb] + bA[1];
      float gf0 = gshA[1][jj0][bb] + bA[2], gf1 = gshA[1][jj0 + 1][bb] + bA[3];
      float gg0 = gshA[2][jj0][bb] + bA[4], gg1 = gshA[2][jj0 + 1][bb] + bA[5];
      float go0 = gshA[3][jj0][bb] + bA[6], go1 = gshA[3][jj0 + 1][bb] + bA[7];
      float cn0 = (1.f / (1.f + __expf(-gf0))) * cA0
                + (1.f / (1.f + __expf(-gi0))) * tanhf(gg0);
      float cn1 = (1.f / (1.f + __expf(-gf1))) * cA1
                + (1.f / (1.f + __expf(-gi1))) * tanhf(gg1);
      cA0 = cn0; cA1 = cn1;
      u32 y0 = (u16)f2bfs((1.f / (1.f + __expf(-go0))) * tanhf(cn0));
      u32 y1 = (u16)f2bfs((1.f / (1.f + __expf(-go1))) * tanhf(cn1));
      __hip_atomic_store((u32*)(yA + bb * 512 + j0 + jj0), y0 | (y1 << 16),
                         __ATOMIC_RELAXED, __HIP_MEMORY_SCOPE_AGENT);
    }
    if (bAct) {
      u16* yB = (k <= 64) ? A.ye1 + (size_t)(k - 1) * NB : A.yd1 + (size_t)(k - 65) * NB;
      float gi0 = gshB[0][jj0][bb] + bB[0], gi1 = gshB[0][jj0 + 1][bb] + bB[1];
      float gf0 = gshB[1][jj0][bb] + bB[2], gf1 = gshB[1][jj0 + 1][bb] + bB[3];
      float gg0 = gshB[2][jj0][bb] + bB[4], gg1 = gshB[2][jj0 + 1][bb] + bB[5];
      float go0 = gshB[3][jj0][bb] + bB[6], go1 = gshB[3][jj0 + 1][bb] + bB[7];
      float cn0 = (1.f / (1.f + __expf(-gf0))) * cB0
                + (1.f / (1.f + __expf(-gi0))) * tanhf(gg0);
      float cn1 = (1.f / (1.f + __expf(-gf1))) * cB1
                + (1.f / (1.f + __expf(-gi1))) * tanhf(gg1);
      cB0 = cn0; cB1 = cn1;
      u32 y0 = (u16)f2bfs((1.f / (1.f + __expf(-go0))) * tanhf(cn0));
      u32 y1 = (u16)f2bfs((1.f / (1.f + __expf(-go1))) * tanhf(cn1));
      __hip_atomic_store((u32*)(yB + bb * 512 + j0 + jj0), y0 | (y1 << 16),
                         __ATOMIC_RELAXED, __HIP_MEMORY_SCOPE_AGENT);
    }
    __syncthreads();   // drains the write-through stores before next arrival
  }
}

// ---------------- projection GEMM: out[b][t][v] = u2[t][b][:] . lin_W[v][:] + lin_b[v]
template<bool BF16>
__device__ __forceinline__ void out_gemm_body(const u16* __restrict__ A,
                                              const void* __restrict__ Wv,
                                              const void* __restrict__ bias,
                                              void* __restrict__ out) {
  __shared__ __align__(16) u16 As[128 * 40];
  __shared__ __align__(16) u16 Bs[128 * 40];
  const int hw = blockIdx.x;                       // 0..3999
  const int logical = (hw & 7) * 500 + (hw >> 3);  // XCD-chunked (4000%8==0)
  const int m0 = (logical & 15) * 128;             // M fastest: 16 tiles
  const int n0 = (logical >> 4) * 128;             // 250 N tiles
  const int tid = threadIdx.x;
  const int lane = tid & 63;
  const int wv = tid >> 6;
  const int wm = wv >> 1, wn = wv & 1;
  const int fr = lane & 15, q8 = (lane >> 4) * 8;
  const int r0 = tid >> 2;
  const int c8 = (tid & 3) * 8;

  f32x4 acc[4][4] = {};

  for (int k0 = 0; k0 < 512; k0 += 32) {
    __syncthreads();
    *(uint4*)&As[r0 * 40 + c8]        = *(const uint4*)&A[(size_t)(m0 + r0) * 512 + k0 + c8];
    *(uint4*)&As[(r0 + 64) * 40 + c8] = *(const uint4*)&A[(size_t)(m0 + r0 + 64) * 512 + k0 + c8];
    *(bf16x8*)&Bs[r0 * 40 + c8]        = ldext8<BF16>(Wv, (size_t)(n0 + r0) * 512 + k0 + c8);
    *(bf16x8*)&Bs[(r0 + 64) * 40 + c8] = ldext8<BF16>(Wv, (size_t)(n0 + r0 + 64) * 512 + k0 + c8);
    __syncthreads();
    bf16x8 af[4], bg[4];
#pragma unroll
    for (int i = 0; i < 4; ++i) {
      af[i] = *(const bf16x8*)&As[(wm * 64 + i * 16 + fr) * 40 + q8];
      bg[i] = *(const bf16x8*)&Bs[(wn * 64 + i * 16 + fr) * 40 + q8];
    }
#pragma unroll
    for (int i = 0; i < 4; ++i)
#pragma unroll
      for (int j = 0; j < 4; ++j)
        acc[i][j] = __builtin_amdgcn_mfma_f32_16x16x32_bf16(af[i], bg[j], acc[i][j], 0, 0, 0);
  }

  const int cl = lane & 15;
  const int rq = (lane >> 4) * 4;
#pragma unroll
  for (int j = 0; j < 4; ++j) {
    int n = n0 + wn * 64 + j * 16 + cl;
    float bv = ldext1<BF16>(bias, n);
#pragma unroll
    for (int i = 0; i < 4; ++i) {
#pragma unroll
      for (int r = 0; r < 4; ++r) {
        int m = m0 + wm * 64 + i * 16 + rq + r;
        int tt = m >> 5, bb = m & 31;
        size_t oidx = ((size_t)bb * T + tt) * VOCAB + n;
        float v = acc[i][j][r] + bv;
        if constexpr (BF16) __builtin_nontemporal_store((u16)f2bfs(v), (u16*)out + oidx);
        else                __builtin_nontemporal_store(v, (float*)out + oidx);
      }
    }
  }
}

__global__ __launch_bounds__(256) void out_gemm_bf16(const u16* A, const void* Wv,
                                                     const void* bias, void* out,
                                                     const int* __restrict__ flag) {
  if (!*flag) return;
  out_gemm_body<true>(A, Wv, bias, out);
}
__global__ __launch_bounds__(256) void out_gemm_f32(const u16* A, const void* Wv,
                                                    const void* bias, void* out,
                                                    const int* __restrict__ flag) {
  if (*flag) return;
  out_gemm_body<false>(A, Wv, bias, out);
}

extern "C" void kernel_launch(void* const* d_in, const int* in_sizes, int n_in,
                              void* d_out, int out_size, void* d_ws, size_t ws_size,
                              hipStream_t stream) {
  (void)in_sizes; (void)n_in; (void)out_size; (void)ws_size;
  const int* x = (const int*)d_in[0];
  const int* tgt = (const int*)d_in[1];
  const void* enc_emb = d_in[2];
  const void* dec_emb = d_in[3];
  const void* Wih[4] = {d_in[4], d_in[7], d_in[10], d_in[13]};
  const void* Whh[4] = {d_in[5], d_in[8], d_in[11], d_in[14]};
  const void* bias[4] = {d_in[6], d_in[9], d_in[12], d_in[15]};
  const void* lin_W = d_in[16];
  const void* lin_b = d_in[17];

  char* ws = (char*)d_ws;
  u16* y_e0   = (u16*)(ws + 0x000000);     // [T][B][H] bf16, 2MB each
  u16* y_e1   = (u16*)(ws + 0x200000);
  u16* y_d0   = (u16*)(ws + 0x400000);
  u16* y_d1   = (u16*)(ws + 0x600000);     // == u2 == GEMM A
  u16* h_zero = (u16*)(ws + 0x800000);     // [B][H] bf16 zeros
  int* flag   = (int*)(ws + 0x810000);
  int* bar    = (int*)(ws + 0x810100);     // persistent-kernel barrier counter
  float* biasf = (float*)(ws + 0x820000);  // [4][2048] f32
  u16* wbf    = (u16*)(ws + 0x830000);     // 8 x [2048][512] bf16 = 16 MB
  float* gxe  = (float*)(ws + 0x1830000);  // [64][2048][32] f32 = 16 MB
  float* gxd  = (float*)(ws + 0x2830000);  // 16 MB; end 0x3830000 (~59 MB)

  dtype_probe<<<dim3(1), 256, 0, stream>>>((const u32*)lin_W, flag);
  init_ws<<<dim3(64), 256, 0, stream>>>(h_zero, bar);

  Ptr8 wsrc;
  for (int l = 0; l < 4; ++l) { wsrc.p[2 * l] = Wih[l]; wsrc.p[2 * l + 1] = Whh[l]; }
  convert_w<<<dim3(1024, 1, 8), 256, 0, stream>>>(wsrc, wbf, flag);

  Ptr8 bsrc = {};
  for (int l = 0; l < 4; ++l) bsrc.p[l] = bias[l];
  convert_b<<<dim3(8, 1, 4), 256, 0, stream>>>(bsrc, biasf, flag);

  gx_gemm_bf16<<<dim3(32, 64, 2), 256, 0, stream>>>(x, tgt, enc_emb, dec_emb, wbf, gxe, gxd, flag);
  gx_gemm_f32 <<<dim3(32, 64, 2), 256, 0, stream>>>(x, tgt, enc_emb, dec_emb, wbf, gxe, gxd, flag);

  PArgs pa;
  pa.wbf = wbf; pa.biasf = biasf; pa.gxe = gxe; pa.gxd = gxd;
  pa.hzero = h_zero;
  pa.ye0 = y_e0; pa.ye1 = y_e1; pa.yd0 = y_d0; pa.yd1 = y_d1;
  pa.bar = bar;
  lstm_persist<<<dim3(32), 256, 0, stream>>>(pa);

  out_gemm_bf16<<<dim3(4000), 256, 0, stream>>>(y_d1, lin_W, lin_b, d_out, flag);
  out_gemm_f32 <<<dim3(4000), 256, 0, stream>>>(y_d1, lin_W, lin_b, d_out, flag);
}